// Round 3
// baseline (489.651 us; speedup 1.0000x reference)
//
#include <hip/hip_runtime.h>
#include <hip/hip_bf16.h>
#include <math.h>

#define Hdim 1024
#define Bdim 32
#define Ldim 2048
#define Mtot (Bdim*Ldim)   // 65536

typedef __attribute__((ext_vector_type(8))) short short8v;
typedef __attribute__((ext_vector_type(4))) short short4v;
typedef __attribute__((ext_vector_type(4))) float floatx4;

static __device__ inline short f2bf(float f) {
    union { float f; unsigned u; } x; x.f = f;
    unsigned r = x.u + 0x7FFF + ((x.u >> 16) & 1);   // RNE
    return (short)(r >> 16);
}

static __device__ inline float fast_tanh(float x) {
    float t = 2.0f * x;
    t = fminf(fmaxf(t, -30.0f), 30.0f);
    float e = __expf(t);
    return (e - 1.0f) / (e + 1.0f);
}

// ---------------- Kernel 1: q[b][o] = hidden[b]·W_h[o] + bias[o] ----------------
__global__ __launch_bounds__(256) void qproj_kernel(
    const float* __restrict__ hidden, const float* __restrict__ attn_w,
    const float* __restrict__ attn_b, float* __restrict__ qbuf)
{
    int w = blockIdx.x * 4 + (threadIdx.x >> 6);   // wave id in [0, 32768)
    int lane = threadIdx.x & 63;
    int o = w >> 5;
    int b = w & 31;
    const float* hrow = hidden + b * Hdim;
    const float* wrow = attn_w + (size_t)o * 2 * Hdim;   // first half = W_h row o
    float s = 0.f;
    #pragma unroll
    for (int i = 0; i < 16; i++) s += hrow[lane + i*64] * wrow[lane + i*64];
    s += __shfl_xor(s, 1);  s += __shfl_xor(s, 2);  s += __shfl_xor(s, 4);
    s += __shfl_xor(s, 8);  s += __shfl_xor(s, 16); s += __shfl_xor(s, 32);
    if (lane == 0) qbuf[b * Hdim + o] = s + attn_b[o];
}

// ---------------- Kernel 2: fused GEMM + tanh + v-dot -> score partials ----------------
// proj[m][o] = sum_k enc[m][k] * W_e[o][k];  spart[nblk][m] = sum_{o in nblk} tanh(proj+q)*v[o]
#define BM 128
#define BN 128
#define BK 32
#define LDST 40   // bf16 elems per LDS row (32 + 8 pad) -> 80B row stride

__global__ __launch_bounds__(256) void scores_kernel(
    const float* __restrict__ enc,      // [Mtot][H]  (enc_flat, m = l*32+b)
    const float* __restrict__ attn_w,   // [H][2H], W_e[o][k] = attn_w[o*2H + H + k]
    const float* __restrict__ qbuf,     // [B][H]
    const float* __restrict__ vvec,     // [H]
    float* __restrict__ spart)          // [8][Mtot]
{
    __shared__ short As[BM * LDST];
    __shared__ short Bs[BN * LDST];
    __shared__ float sred[BM][2];

    int bx    = blockIdx.x;
    int nblk  = bx & 7;
    int mtile = bx >> 3;
    int m0 = mtile * BM;
    int n0 = nblk * BN;

    int tid  = threadIdx.x;
    int wid  = tid >> 6;
    int lane = tid & 63;
    int wr = wid >> 1, wc = wid & 1;
    int r15 = lane & 15;
    int kc  = lane >> 4;          // 0..3 k-chunk

    floatx4 acc[4][4];
    #pragma unroll
    for (int i = 0; i < 4; i++)
        #pragma unroll
        for (int j = 0; j < 4; j++) acc[i][j] = (floatx4){0.f, 0.f, 0.f, 0.f};

    for (int k0 = 0; k0 < Hdim; k0 += BK) {
        __syncthreads();   // protect LDS vs previous iteration's reads
        // ---- stage A (128x32) and B (128x32), f32 -> bf16 ----
        #pragma unroll
        for (int i = 0; i < 4; i++) {
            int slot = tid + i * 256;        // 0..1023
            int row  = slot >> 3;            // 0..127
            int c4   = slot & 7;             // float4 column
            float4 av = *(const float4*)(enc + (size_t)(m0 + row) * Hdim + k0 + c4 * 4);
            short4v as; as.x = f2bf(av.x); as.y = f2bf(av.y); as.z = f2bf(av.z); as.w = f2bf(av.w);
            *(short4v*)(&As[row * LDST + c4 * 4]) = as;
            float4 bv = *(const float4*)(attn_w + (size_t)(n0 + row) * 2 * Hdim + Hdim + k0 + c4 * 4);
            short4v bs; bs.x = f2bf(bv.x); bs.y = f2bf(bv.y); bs.z = f2bf(bv.z); bs.w = f2bf(bv.w);
            *(short4v*)(&Bs[row * LDST + c4 * 4]) = bs;
        }
        __syncthreads();
        // ---- fragments + MFMA ----
        short8v af[4], bf[4];
        #pragma unroll
        for (int mi = 0; mi < 4; mi++)
            af[mi] = *(const short8v*)(&As[(wr*64 + mi*16 + r15) * LDST + kc * 8]);
        #pragma unroll
        for (int ni = 0; ni < 4; ni++)
            bf[ni] = *(const short8v*)(&Bs[(wc*64 + ni*16 + r15) * LDST + kc * 8]);
        #pragma unroll
        for (int mi = 0; mi < 4; mi++)
            #pragma unroll
            for (int ni = 0; ni < 4; ni++)
                acc[mi][ni] = __builtin_amdgcn_mfma_f32_16x16x32_bf16(af[mi], bf[ni], acc[mi][ni], 0, 0, 0);
    }

    // ---- epilogue: tanh(proj + q) * v, reduce over this block's 128 cols ----
    int rg = lane >> 4;
    #pragma unroll
    for (int mi = 0; mi < 4; mi++) {
        float rs[4] = {0.f, 0.f, 0.f, 0.f};
        #pragma unroll
        for (int ni = 0; ni < 4; ni++) {
            int o = n0 + wc*64 + ni*16 + r15;
            float vo = vvec[o];
            #pragma unroll
            for (int reg = 0; reg < 4; reg++) {
                int trow = wr*64 + mi*16 + rg*4 + reg;   // tile row (m0 is mult of 32)
                int b = trow & 31;
                float p = acc[mi][ni][reg] + qbuf[b * Hdim + o];
                rs[reg] += fast_tanh(p) * vo;
            }
        }
        #pragma unroll
        for (int reg = 0; reg < 4; reg++) {
            float s = rs[reg];
            s += __shfl_xor(s, 1); s += __shfl_xor(s, 2);
            s += __shfl_xor(s, 4); s += __shfl_xor(s, 8);
            if (r15 == 0) {
                int trow = wr*64 + mi*16 + rg*4 + reg;
                sred[trow][wc] = s;
            }
        }
    }
    __syncthreads();
    if (tid < BM)
        spart[(size_t)nblk * Mtot + m0 + tid] = sred[tid][0] + sred[tid][1];
}

// ---------------- Kernel 3: reduce partials + softmax over L (per b) ----------------
__global__ __launch_bounds__(256) void softmax_kernel(
    const float* __restrict__ spart,   // [8][Mtot], m = l*32+b
    float* __restrict__ attn)          // [B][L]
{
    int b = blockIdx.x;
    int t = threadIdx.x;
    __shared__ float rmax[4], rsum[4];
    float sv[8];
    float mx = -1e30f;
    #pragma unroll
    for (int i = 0; i < 8; i++) {
        int l = t + i * 256;
        int m = l * Bdim + b;
        float s = 0.f;
        #pragma unroll
        for (int p = 0; p < 8; p++) s += spart[(size_t)p * Mtot + m];
        sv[i] = s;
        mx = fmaxf(mx, s);
    }
    #pragma unroll
    for (int off = 1; off < 64; off <<= 1) mx = fmaxf(mx, __shfl_xor(mx, off));
    if ((t & 63) == 0) rmax[t >> 6] = mx;
    __syncthreads();
    mx = fmaxf(fmaxf(rmax[0], rmax[1]), fmaxf(rmax[2], rmax[3]));
    float sum = 0.f;
    #pragma unroll
    for (int i = 0; i < 8; i++) { sv[i] = __expf(sv[i] - mx); sum += sv[i]; }
    #pragma unroll
    for (int off = 1; off < 64; off <<= 1) sum += __shfl_xor(sum, off);
    if ((t & 63) == 0) rsum[t >> 6] = sum;
    __syncthreads();
    sum = rsum[0] + rsum[1] + rsum[2] + rsum[3];
    float inv = 1.f / sum;
    #pragma unroll
    for (int i = 0; i < 8; i++)
        attn[(size_t)b * Ldim + t + i * 256] = sv[i] * inv;
}

// ---------------- Kernel 4: context partials over L-chunks ----------------
__global__ __launch_bounds__(256) void context_part_kernel(
    const float* __restrict__ enc,    // [L*B][H]
    const float* __restrict__ attn,   // [B][L]
    float* __restrict__ cpart)        // [64][B][H]
{
    int b = blockIdx.x & 31;
    int c = blockIdx.x >> 5;          // 0..63
    int t = threadIdx.x;
    float4 acc = {0.f, 0.f, 0.f, 0.f};
    int l0 = c * 32;
    for (int i = 0; i < 32; i++) {
        int l = l0 + i;
        float a = attn[(size_t)b * Ldim + l];
        float4 e = *(const float4*)(enc + (size_t)(l * Bdim + b) * Hdim + t * 4);
        acc.x += a * e.x; acc.y += a * e.y; acc.z += a * e.z; acc.w += a * e.w;
    }
    *(float4*)(cpart + ((size_t)c * Bdim + b) * Hdim + t * 4) = acc;
}

// ---------------- Kernel 5: reduce context partials ----------------
__global__ __launch_bounds__(256) void context_reduce_kernel(
    const float* __restrict__ cpart, float* __restrict__ out)
{
    int idx = blockIdx.x * 256 + threadIdx.x;    // 0..32767 = b*H + h
    float s = 0.f;
    for (int c = 0; c < 64; c++) s += cpart[(size_t)c * (Bdim * Hdim) + idx];
    out[idx] = s;
}

extern "C" void kernel_launch(void* const* d_in, const int* in_sizes, int n_in,
                              void* d_out, int out_size, void* d_ws, size_t ws_size,
                              hipStream_t stream)
{
    const float* hidden = (const float*)d_in[0];
    const float* enc    = (const float*)d_in[1];   // (L,B,H) = flat [Mtot][H], m=l*32+b
    const float* attn_w = (const float*)d_in[2];
    const float* attn_b = (const float*)d_in[3];
    const float* vvec   = (const float*)d_in[4];
    float* out = (float*)d_out;

    char* ws = (char*)d_ws;
    float* qbuf  = (float*)(ws);                                  // 32*1024*4      = 128 KB
    float* spart = (float*)(ws + (131072));                       // 8*65536*4      = 2 MB
    float* attnp = (float*)(ws + (131072 + 2097152));             // 65536*4        = 256 KB
    float* cpart = (float*)(ws + (131072 + 2097152 + 262144));    // 64*32768*4     = 8 MB
    // total ws usage ~10.4 MB

    qproj_kernel<<<8192, 256, 0, stream>>>(hidden, attn_w, attn_b, qbuf);
    scores_kernel<<<4096, 256, 0, stream>>>(enc, attn_w, qbuf, vvec, spart);
    softmax_kernel<<<Bdim, 256, 0, stream>>>(spart, attnp);
    context_part_kernel<<<2048, 256, 0, stream>>>(enc, attnp, cpart);
    context_reduce_kernel<<<128, 256, 0, stream>>>(cpart, out);
}

// Round 5
// 351.861 us; speedup vs baseline: 1.3916x; 1.3916x over previous
//
#include <hip/hip_runtime.h>
#include <hip/hip_bf16.h>
#include <math.h>

#define Hdim 1024
#define Bdim 32
#define Ldim 2048
#define Mtot (Bdim*Ldim)   // 65536

typedef __attribute__((ext_vector_type(8))) short short8v;
typedef __attribute__((ext_vector_type(4))) short short4v;
typedef __attribute__((ext_vector_type(4))) float floatx4;

static __device__ inline short f2bf(float f) {
    union { float f; unsigned u; } x; x.f = f;
    unsigned r = x.u + 0x7FFF + ((x.u >> 16) & 1);   // RNE
    return (short)(r >> 16);
}
static __device__ inline float bf2f(short s) {
    union { unsigned u; float f; } x; x.u = ((unsigned)(unsigned short)s) << 16;
    return x.f;
}

static __device__ inline float fast_tanh(float x) {
    float t = 2.0f * x;
    t = fminf(fmaxf(t, -30.0f), 30.0f);
    float e = __expf(t);
    return (e - 1.0f) / (e + 1.0f);
}

typedef __attribute__((address_space(1))) const void GVT;
typedef __attribute__((address_space(3))) void LVT;
static __device__ inline void gload_lds16(const void* g, void* l) {
    __builtin_amdgcn_global_load_lds((GVT*)g, (LVT*)l, 16, 0, 0);
}

// ---------------- Kernel 0a: enc f32 -> bf16 (one-time, BW-bound) ----------------
__global__ __launch_bounds__(256) void convert_enc_kernel(
    const float* __restrict__ enc, short* __restrict__ enc_bf)
{
    size_t i = ((size_t)blockIdx.x * 256 + threadIdx.x) * 8;
    float4 a = *(const float4*)(enc + i);
    float4 b = *(const float4*)(enc + i + 4);
    short8v o;
    o[0]=f2bf(a.x); o[1]=f2bf(a.y); o[2]=f2bf(a.z); o[3]=f2bf(a.w);
    o[4]=f2bf(b.x); o[5]=f2bf(b.y); o[6]=f2bf(b.z); o[7]=f2bf(b.w);
    *(short8v*)(enc_bf + i) = o;
}

// ---------------- Kernel 0b: W_e (= attn_w[:, H:]) f32 -> compact bf16 [1024][1024] ----------------
__global__ __launch_bounds__(256) void convert_w_kernel(
    const float* __restrict__ attn_w, short* __restrict__ w_bf)
{
    int t = blockIdx.x * 256 + threadIdx.x;   // 0..131071
    int o = t >> 7;                           // row 0..1023
    int c = t & 127;                          // 8-elem chunk
    const float* src = attn_w + (size_t)o * 2 * Hdim + Hdim + c * 8;
    float4 a = *(const float4*)(src);
    float4 b = *(const float4*)(src + 4);
    short8v v;
    v[0]=f2bf(a.x); v[1]=f2bf(a.y); v[2]=f2bf(a.z); v[3]=f2bf(a.w);
    v[4]=f2bf(b.x); v[5]=f2bf(b.y); v[6]=f2bf(b.z); v[7]=f2bf(b.w);
    *(short8v*)(w_bf + (size_t)o * Hdim + c * 8) = v;
}

// ---------------- Kernel 1: q[b][o] = hidden[b]·W_h[o] + bias[o] ----------------
__global__ __launch_bounds__(256) void qproj_kernel(
    const float* __restrict__ hidden, const float* __restrict__ attn_w,
    const float* __restrict__ attn_b, float* __restrict__ qbuf)
{
    int w = blockIdx.x * 4 + (threadIdx.x >> 6);
    int lane = threadIdx.x & 63;
    int o = w >> 5;
    int b = w & 31;
    const float* hrow = hidden + b * Hdim;
    const float* wrow = attn_w + (size_t)o * 2 * Hdim;
    float s = 0.f;
    #pragma unroll
    for (int i = 0; i < 16; i++) s += hrow[lane + i*64] * wrow[lane + i*64];
    s += __shfl_xor(s, 1);  s += __shfl_xor(s, 2);  s += __shfl_xor(s, 4);
    s += __shfl_xor(s, 8);  s += __shfl_xor(s, 16); s += __shfl_xor(s, 32);
    if (lane == 0) qbuf[b * Hdim + o] = s + attn_b[o];
}

// ---------------- Kernel 2: m97-style bf16 GEMM + tanh + v-dot -> score partials ----------------
#define BM 128
#define BN 128
#define BK 32

__global__ __launch_bounds__(256) void scores_kernel(
    const short* __restrict__ enc_bf,   // [Mtot][1024] bf16
    const short* __restrict__ w_bf,     // [1024][1024] bf16
    const float* __restrict__ qbuf,     // [B][H]
    const float* __restrict__ vvec,     // [H]
    float* __restrict__ spart)          // [8][Mtot]
{
    __shared__ short As[BM * BK];       // 8 KB, linear rows of 64B
    __shared__ short Bs[BN * BK];       // 8 KB
    __shared__ float sred[BM][2];

    int bx    = blockIdx.x;
    int nblk  = bx & 7;
    int mtile = bx >> 3;
    int m0 = mtile * BM;
    int n0 = nblk * BN;

    int tid  = threadIdx.x;
    int w    = tid >> 6;
    int l    = tid & 63;
    int wr = w >> 1, wc = w & 1;
    int r15 = l & 15;
    int kc  = l >> 4;

    // staging: wave w covers rows [w*32, w*32+32); issue i covers 16 rows.
    // lane l -> row sub = l/4, 16B chunk = l%4. LDS dest linear: base + l*16.
    int subrow = l >> 2;
    int chunk  = l & 3;
    const short* ag0 = enc_bf + (size_t)(m0 + w*32 + subrow) * Hdim + chunk * 8;
    const short* ag1 = ag0 + (size_t)16 * Hdim;
    const short* bg0 = w_bf  + (size_t)(n0 + w*32 + subrow) * Hdim + chunk * 8;
    const short* bg1 = bg0 + (size_t)16 * Hdim;
    short* al0 = As + (w*32) * BK;
    short* al1 = As + (w*32 + 16) * BK;
    short* bl0 = Bs + (w*32) * BK;
    short* bl1 = Bs + (w*32 + 16) * BK;

    // fragment read offsets (constant)
    int aoff[4], boff[4];
    #pragma unroll
    for (int i = 0; i < 4; i++) {
        aoff[i] = (wr*64 + i*16 + r15) * BK + kc * 8;
        boff[i] = (wc*64 + i*16 + r15) * BK + kc * 8;
    }

    floatx4 acc[4][4];
    #pragma unroll
    for (int i = 0; i < 4; i++)
        #pragma unroll
        for (int j = 0; j < 4; j++) acc[i][j] = (floatx4){0.f, 0.f, 0.f, 0.f};

    for (int kt = 0; kt < Hdim / BK; kt++) {
        __syncthreads();                       // prev-iter LDS reads done
        gload_lds16(ag0, al0);
        gload_lds16(ag1, al1);
        gload_lds16(bg0, bl0);
        gload_lds16(bg1, bl1);
        ag0 += BK; ag1 += BK; bg0 += BK; bg1 += BK;
        __syncthreads();                       // drains vmcnt before barrier

        short8v af[4], bf[4];
        #pragma unroll
        for (int mi = 0; mi < 4; mi++) af[mi] = *(const short8v*)(&As[aoff[mi]]);
        #pragma unroll
        for (int ni = 0; ni < 4; ni++) bf[ni] = *(const short8v*)(&Bs[boff[ni]]);
        #pragma unroll
        for (int mi = 0; mi < 4; mi++)
            #pragma unroll
            for (int ni = 0; ni < 4; ni++)
                acc[mi][ni] = __builtin_amdgcn_mfma_f32_16x16x32_bf16(af[mi], bf[ni], acc[mi][ni], 0, 0, 0);
    }

    // ---- epilogue: tanh(proj + q) * v, reduce over this block's 128 cols ----
    int rg = l >> 4;
    #pragma unroll
    for (int mi = 0; mi < 4; mi++) {
        float rs[4] = {0.f, 0.f, 0.f, 0.f};
        #pragma unroll
        for (int ni = 0; ni < 4; ni++) {
            int o = n0 + wc*64 + ni*16 + r15;
            float vo = vvec[o];
            #pragma unroll
            for (int reg = 0; reg < 4; reg++) {
                int trow = wr*64 + mi*16 + rg*4 + reg;
                int b = trow & 31;
                float p = acc[mi][ni][reg] + qbuf[b * Hdim + o];
                rs[reg] += fast_tanh(p) * vo;
            }
        }
        #pragma unroll
        for (int reg = 0; reg < 4; reg++) {
            float s = rs[reg];
            s += __shfl_xor(s, 1); s += __shfl_xor(s, 2);
            s += __shfl_xor(s, 4); s += __shfl_xor(s, 8);
            if (r15 == 0) {
                int trow = wr*64 + mi*16 + rg*4 + reg;
                sred[trow][wc] = s;
            }
        }
    }
    __syncthreads();
    if (tid < BM)
        spart[(size_t)nblk * Mtot + m0 + tid] = sred[tid][0] + sred[tid][1];
}

// ---------------- Kernel 3: reduce partials + softmax over L (per b) ----------------
__global__ __launch_bounds__(256) void softmax_kernel(
    const float* __restrict__ spart, float* __restrict__ attn)
{
    int b = blockIdx.x;
    int t = threadIdx.x;
    __shared__ float rmax[4], rsum[4];
    float sv[8];
    float mx = -1e30f;
    #pragma unroll
    for (int i = 0; i < 8; i++) {
        int l = t + i * 256;
        int m = l * Bdim + b;
        float s = 0.f;
        #pragma unroll
        for (int p = 0; p < 8; p++) s += spart[(size_t)p * Mtot + m];
        sv[i] = s;
        mx = fmaxf(mx, s);
    }
    #pragma unroll
    for (int off = 1; off < 64; off <<= 1) mx = fmaxf(mx, __shfl_xor(mx, off));
    if ((t & 63) == 0) rmax[t >> 6] = mx;
    __syncthreads();
    mx = fmaxf(fmaxf(rmax[0], rmax[1]), fmaxf(rmax[2], rmax[3]));
    float sum = 0.f;
    #pragma unroll
    for (int i = 0; i < 8; i++) { sv[i] = __expf(sv[i] - mx); sum += sv[i]; }
    #pragma unroll
    for (int off = 1; off < 64; off <<= 1) sum += __shfl_xor(sum, off);
    if ((t & 63) == 0) rsum[t >> 6] = sum;
    __syncthreads();
    sum = rsum[0] + rsum[1] + rsum[2] + rsum[3];
    float inv = 1.f / sum;
    #pragma unroll
    for (int i = 0; i < 8; i++)
        attn[(size_t)b * Ldim + t + i * 256] = sv[i] * inv;
}

// ---------------- Kernel 4: context partials over L-chunks (bf16 enc) ----------------
__global__ __launch_bounds__(256) void context_part_kernel(
    const short* __restrict__ enc_bf,  // [L*B][H] bf16
    const float* __restrict__ attn,    // [B][L]
    float* __restrict__ cpart)         // [64][B][H]
{
    int b = blockIdx.x & 31;
    int c = blockIdx.x >> 5;
    int t = threadIdx.x;
    float a0 = 0.f, a1 = 0.f, a2 = 0.f, a3 = 0.f;
    int l0 = c * 32;
    for (int i = 0; i < 32; i++) {
        int l = l0 + i;
        float a = attn[(size_t)b * Ldim + l];
        short4v e = *(const short4v*)(enc_bf + (size_t)(l * Bdim + b) * Hdim + t * 4);
        a0 += a * bf2f(e.x); a1 += a * bf2f(e.y);
        a2 += a * bf2f(e.z); a3 += a * bf2f(e.w);
    }
    float4 r; r.x = a0; r.y = a1; r.z = a2; r.w = a3;
    *(float4*)(cpart + ((size_t)c * Bdim + b) * Hdim + t * 4) = r;
}

// ---------------- Kernel 5: reduce context partials ----------------
__global__ __launch_bounds__(256) void context_reduce_kernel(
    const float* __restrict__ cpart, float* __restrict__ out)
{
    int idx = blockIdx.x * 256 + threadIdx.x;
    float s = 0.f;
    for (int c = 0; c < 64; c++) s += cpart[(size_t)c * (Bdim * Hdim) + idx];
    out[idx] = s;
}

extern "C" void kernel_launch(void* const* d_in, const int* in_sizes, int n_in,
                              void* d_out, int out_size, void* d_ws, size_t ws_size,
                              hipStream_t stream)
{
    const float* hidden = (const float*)d_in[0];
    const float* enc    = (const float*)d_in[1];   // (L,B,H), m = l*32+b
    const float* attn_w = (const float*)d_in[2];
    const float* attn_b = (const float*)d_in[3];
    const float* vvec   = (const float*)d_in[4];
    float* out = (float*)d_out;

    char* ws = (char*)d_ws;
    size_t off = 0;
    short* enc_bf = (short*)(ws + off); off += (size_t)Mtot * Hdim * 2;       // 134.2 MB
    short* w_bf   = (short*)(ws + off); off += (size_t)Hdim * Hdim * 2;       //   2.1 MB
    float* qbuf   = (float*)(ws + off); off += (size_t)Bdim * Hdim * 4;       //   0.13 MB
    float* spart  = (float*)(ws + off); off += (size_t)8 * Mtot * 4;          //   2.1 MB
    float* attnp  = (float*)(ws + off); off += (size_t)Mtot * 4;              //   0.26 MB
    float* cpart  = (float*)(ws + off);                                       //   8.4 MB
    // total ~147 MB

    convert_enc_kernel<<<32768, 256, 0, stream>>>(enc, enc_bf);
    convert_w_kernel<<<512, 256, 0, stream>>>(attn_w, w_bf);
    qproj_kernel<<<8192, 256, 0, stream>>>(hidden, attn_w, attn_b, qbuf);
    scores_kernel<<<4096, 256, 0, stream>>>(enc_bf, w_bf, qbuf, vvec, spart);
    softmax_kernel<<<Bdim, 256, 0, stream>>>(spart, attnp);
    context_part_kernel<<<2048, 256, 0, stream>>>(enc_bf, attnp, cpart);
    context_reduce_kernel<<<128, 256, 0, stream>>>(cpart, out);
}

// Round 6
// 306.656 us; speedup vs baseline: 1.5967x; 1.1474x over previous
//
#include <hip/hip_runtime.h>
#include <hip/hip_bf16.h>
#include <math.h>

#define Hdim 1024
#define Bdim 32
#define Ldim 2048
#define Mtot (Bdim*Ldim)   // 65536

typedef __attribute__((ext_vector_type(8))) short short8v;
typedef __attribute__((ext_vector_type(4))) short short4v;
typedef __attribute__((ext_vector_type(4))) float floatx4;

static __device__ inline short f2bf(float f) {
    union { float f; unsigned u; } x; x.f = f;
    unsigned r = x.u + 0x7FFF + ((x.u >> 16) & 1);   // RNE
    return (short)(r >> 16);
}
static __device__ inline float bf2f(short s) {
    union { unsigned u; float f; } x; x.u = ((unsigned)(unsigned short)s) << 16;
    return x.f;
}

static __device__ inline float fast_tanh(float x) {
    float t = 2.0f * x;
    t = fminf(fmaxf(t, -30.0f), 30.0f);
    float e = __expf(t);
    return (e - 1.0f) / (e + 1.0f);
}

typedef __attribute__((address_space(1))) const void GVT;
typedef __attribute__((address_space(3))) void LVT;
static __device__ inline void gload_lds16(const void* g, void* l) {
    __builtin_amdgcn_global_load_lds((GVT*)g, (LVT*)l, 16, 0, 0);
}

// ---------------- Kernel 0a: enc f32 -> bf16 (one-time, BW-bound) ----------------
__global__ __launch_bounds__(256) void convert_enc_kernel(
    const float* __restrict__ enc, short* __restrict__ enc_bf)
{
    size_t i = ((size_t)blockIdx.x * 256 + threadIdx.x) * 8;
    float4 a = *(const float4*)(enc + i);
    float4 b = *(const float4*)(enc + i + 4);
    short8v o;
    o[0]=f2bf(a.x); o[1]=f2bf(a.y); o[2]=f2bf(a.z); o[3]=f2bf(a.w);
    o[4]=f2bf(b.x); o[5]=f2bf(b.y); o[6]=f2bf(b.z); o[7]=f2bf(b.w);
    *(short8v*)(enc_bf + i) = o;
}

// ---------------- Kernel 0b: W_e (= attn_w[:, H:]) f32 -> compact bf16 [1024][1024] ----------------
__global__ __launch_bounds__(256) void convert_w_kernel(
    const float* __restrict__ attn_w, short* __restrict__ w_bf)
{
    int t = blockIdx.x * 256 + threadIdx.x;   // 0..131071
    int o = t >> 7;                           // row 0..1023
    int c = t & 127;                          // 8-elem chunk
    const float* src = attn_w + (size_t)o * 2 * Hdim + Hdim + c * 8;
    float4 a = *(const float4*)(src);
    float4 b = *(const float4*)(src + 4);
    short8v v;
    v[0]=f2bf(a.x); v[1]=f2bf(a.y); v[2]=f2bf(a.z); v[3]=f2bf(a.w);
    v[4]=f2bf(b.x); v[5]=f2bf(b.y); v[6]=f2bf(b.z); v[7]=f2bf(b.w);
    *(short8v*)(w_bf + (size_t)o * Hdim + c * 8) = v;
}

// ---------------- Kernel 1: q[b][o] = hidden[b]·W_h[o] + bias[o] ----------------
__global__ __launch_bounds__(256) void qproj_kernel(
    const float* __restrict__ hidden, const float* __restrict__ attn_w,
    const float* __restrict__ attn_b, float* __restrict__ qbuf)
{
    int w = blockIdx.x * 4 + (threadIdx.x >> 6);
    int lane = threadIdx.x & 63;
    int o = w >> 5;
    int b = w & 31;
    const float* hrow = hidden + b * Hdim;
    const float* wrow = attn_w + (size_t)o * 2 * Hdim;
    float s = 0.f;
    #pragma unroll
    for (int i = 0; i < 16; i++) s += hrow[lane + i*64] * wrow[lane + i*64];
    s += __shfl_xor(s, 1);  s += __shfl_xor(s, 2);  s += __shfl_xor(s, 4);
    s += __shfl_xor(s, 8);  s += __shfl_xor(s, 16); s += __shfl_xor(s, 32);
    if (lane == 0) qbuf[b * Hdim + o] = s + attn_b[o];
}

// ---------------- Kernel 2: dbuf-prefetch bf16 GEMM + tanh + v-dot -> score partials ----------------
#define BM 128
#define BN 128
#define BK 32

__global__ __launch_bounds__(256, 4) void scores_kernel(
    const short* __restrict__ enc_bf,   // [Mtot][1024] bf16
    const short* __restrict__ w_bf,     // [1024][1024] bf16
    const float* __restrict__ qbuf,     // [B][H]
    const float* __restrict__ vvec,     // [H]
    float* __restrict__ spart)          // [8][Mtot]
{
    __shared__ short As[2][BM * BK];    // 2 x 8 KB, linear rows of 64B
    __shared__ short Bs[2][BN * BK];    // 2 x 8 KB
    __shared__ float sred[BM][2];

    // XCD-aware swizzle: put the 8 nblk blocks sharing one A-panel on ONE XCD
    // (assumes consecutive blockIdx round-robins the 8 XCDs). grid = 4096 = 8*512.
    int hw = blockIdx.x;
    int xcd = hw & 7;
    int i5  = hw >> 3;                  // 0..511 within-XCD order
    int nblk  = i5 & 7;                 // fastest: 8 sharers consecutive on XCD
    int mtile = xcd * 64 + (i5 >> 3);   // 0..511, bijective
    int m0 = mtile * BM;
    int n0 = nblk * BN;

    int tid  = threadIdx.x;
    int w    = tid >> 6;
    int l    = tid & 63;
    int wr = w >> 1, wc = w & 1;
    int r15 = l & 15;
    int kc  = l >> 4;

    // staging: wave w covers rows [w*32, w*32+32); two issues of 16 rows.
    // lane l -> row sub = l/4, 16B chunk = l%4. LDS dest linear: base + l*16.
    int subrow = l >> 2;
    int chunk  = l & 3;
    const short* ag0 = enc_bf + (size_t)(m0 + w*32 + subrow) * Hdim + chunk * 8;
    const short* ag1 = ag0 + (size_t)16 * Hdim;
    const short* bg0 = w_bf  + (size_t)(n0 + w*32 + subrow) * Hdim + chunk * 8;
    const short* bg1 = bg0 + (size_t)16 * Hdim;
    int al0 = (w*32) * BK;
    int al1 = (w*32 + 16) * BK;

    // fragment read offsets (constant per lane)
    int aoff[4], boff[4];
    #pragma unroll
    for (int i = 0; i < 4; i++) {
        aoff[i] = (wr*64 + i*16 + r15) * BK + kc * 8;
        boff[i] = (wc*64 + i*16 + r15) * BK + kc * 8;
    }

    floatx4 acc[4][4];
    #pragma unroll
    for (int i = 0; i < 4; i++)
        #pragma unroll
        for (int j = 0; j < 4; j++) acc[i][j] = (floatx4){0.f, 0.f, 0.f, 0.f};

    // prologue: stage tile 0 into buf 0
    gload_lds16(ag0, &As[0][al0]);
    gload_lds16(ag1, &As[0][al1]);
    gload_lds16(bg0, &Bs[0][al0]);
    gload_lds16(bg1, &Bs[0][al1]);
    ag0 += BK; ag1 += BK; bg0 += BK; bg1 += BK;
    __syncthreads();                    // vmcnt(0) drain + barrier

    #pragma unroll 2
    for (int kt = 0; kt < Hdim / BK; kt++) {
        int cur = kt & 1;
        // issue next-tile prefetch into the other buffer (overlaps with MFMA below)
        if (kt < Hdim / BK - 1) {
            int nxt = cur ^ 1;
            gload_lds16(ag0, &As[nxt][al0]);
            gload_lds16(ag1, &As[nxt][al1]);
            gload_lds16(bg0, &Bs[nxt][al0]);
            gload_lds16(bg1, &Bs[nxt][al1]);
            ag0 += BK; ag1 += BK; bg0 += BK; bg1 += BK;
        }
        short8v af[4], bf[4];
        #pragma unroll
        for (int mi = 0; mi < 4; mi++) af[mi] = *(const short8v*)(&As[cur][aoff[mi]]);
        #pragma unroll
        for (int ni = 0; ni < 4; ni++) bf[ni] = *(const short8v*)(&Bs[cur][boff[ni]]);
        #pragma unroll
        for (int mi = 0; mi < 4; mi++)
            #pragma unroll
            for (int ni = 0; ni < 4; ni++)
                acc[mi][ni] = __builtin_amdgcn_mfma_f32_16x16x32_bf16(af[mi], bf[ni], acc[mi][ni], 0, 0, 0);
        __syncthreads();                // drains prefetch (vmcnt0) + LDS reads done
    }

    // ---- epilogue: tanh(proj + q) * v, reduce over this block's 128 cols ----
    int rg = l >> 4;
    #pragma unroll
    for (int mi = 0; mi < 4; mi++) {
        float rs[4] = {0.f, 0.f, 0.f, 0.f};
        #pragma unroll
        for (int ni = 0; ni < 4; ni++) {
            int o = n0 + wc*64 + ni*16 + r15;
            float vo = vvec[o];
            #pragma unroll
            for (int reg = 0; reg < 4; reg++) {
                int trow = wr*64 + mi*16 + rg*4 + reg;
                int b = trow & 31;
                float p = acc[mi][ni][reg] + qbuf[b * Hdim + o];
                rs[reg] += fast_tanh(p) * vo;
            }
        }
        #pragma unroll
        for (int reg = 0; reg < 4; reg++) {
            float s = rs[reg];
            s += __shfl_xor(s, 1); s += __shfl_xor(s, 2);
            s += __shfl_xor(s, 4); s += __shfl_xor(s, 8);
            if (r15 == 0) {
                int trow = wr*64 + mi*16 + rg*4 + reg;
                sred[trow][wc] = s;
            }
        }
    }
    __syncthreads();
    if (tid < BM)
        spart[(size_t)nblk * Mtot + m0 + tid] = sred[tid][0] + sred[tid][1];
}

// ---------------- Kernel 3: reduce partials + softmax over L (per b) ----------------
__global__ __launch_bounds__(256) void softmax_kernel(
    const float* __restrict__ spart, float* __restrict__ attn)
{
    int b = blockIdx.x;
    int t = threadIdx.x;
    __shared__ float rmax[4], rsum[4];
    float sv[8];
    float mx = -1e30f;
    #pragma unroll
    for (int i = 0; i < 8; i++) {
        int l = t + i * 256;
        int m = l * Bdim + b;
        float s = 0.f;
        #pragma unroll
        for (int p = 0; p < 8; p++) s += spart[(size_t)p * Mtot + m];
        sv[i] = s;
        mx = fmaxf(mx, s);
    }
    #pragma unroll
    for (int off = 1; off < 64; off <<= 1) mx = fmaxf(mx, __shfl_xor(mx, off));
    if ((t & 63) == 0) rmax[t >> 6] = mx;
    __syncthreads();
    mx = fmaxf(fmaxf(rmax[0], rmax[1]), fmaxf(rmax[2], rmax[3]));
    float sum = 0.f;
    #pragma unroll
    for (int i = 0; i < 8; i++) { sv[i] = __expf(sv[i] - mx); sum += sv[i]; }
    #pragma unroll
    for (int off = 1; off < 64; off <<= 1) sum += __shfl_xor(sum, off);
    if ((t & 63) == 0) rsum[t >> 6] = sum;
    __syncthreads();
    sum = rsum[0] + rsum[1] + rsum[2] + rsum[3];
    float inv = 1.f / sum;
    #pragma unroll
    for (int i = 0; i < 8; i++)
        attn[(size_t)b * Ldim + t + i * 256] = sv[i] * inv;
}

// ---------------- Kernel 4: context partials over L-chunks (bf16 enc) ----------------
__global__ __launch_bounds__(256) void context_part_kernel(
    const short* __restrict__ enc_bf,  // [L*B][H] bf16
    const float* __restrict__ attn,    // [B][L]
    float* __restrict__ cpart)         // [64][B][H]
{
    int b = blockIdx.x & 31;
    int c = blockIdx.x >> 5;
    int t = threadIdx.x;
    float a0 = 0.f, a1 = 0.f, a2 = 0.f, a3 = 0.f;
    int l0 = c * 32;
    for (int i = 0; i < 32; i++) {
        int l = l0 + i;
        float a = attn[(size_t)b * Ldim + l];
        short4v e = *(const short4v*)(enc_bf + (size_t)(l * Bdim + b) * Hdim + t * 4);
        a0 += a * bf2f(e.x); a1 += a * bf2f(e.y);
        a2 += a * bf2f(e.z); a3 += a * bf2f(e.w);
    }
    float4 r; r.x = a0; r.y = a1; r.z = a2; r.w = a3;
    *(float4*)(cpart + ((size_t)c * Bdim + b) * Hdim + t * 4) = r;
}

// ---------------- Kernel 5: reduce context partials ----------------
__global__ __launch_bounds__(256) void context_reduce_kernel(
    const float* __restrict__ cpart, float* __restrict__ out)
{
    int idx = blockIdx.x * 256 + threadIdx.x;
    float s = 0.f;
    for (int c = 0; c < 64; c++) s += cpart[(size_t)c * (Bdim * Hdim) + idx];
    out[idx] = s;
}

extern "C" void kernel_launch(void* const* d_in, const int* in_sizes, int n_in,
                              void* d_out, int out_size, void* d_ws, size_t ws_size,
                              hipStream_t stream)
{
    const float* hidden = (const float*)d_in[0];
    const float* enc    = (const float*)d_in[1];   // (L,B,H), m = l*32+b
    const float* attn_w = (const float*)d_in[2];
    const float* attn_b = (const float*)d_in[3];
    const float* vvec   = (const float*)d_in[4];
    float* out = (float*)d_out;

    char* ws = (char*)d_ws;
    size_t off = 0;
    short* enc_bf = (short*)(ws + off); off += (size_t)Mtot * Hdim * 2;       // 134.2 MB
    short* w_bf   = (short*)(ws + off); off += (size_t)Hdim * Hdim * 2;       //   2.1 MB
    float* qbuf   = (float*)(ws + off); off += (size_t)Bdim * Hdim * 4;       //   0.13 MB
    float* spart  = (float*)(ws + off); off += (size_t)8 * Mtot * 4;          //   2.1 MB
    float* attnp  = (float*)(ws + off); off += (size_t)Mtot * 4;              //   0.26 MB
    float* cpart  = (float*)(ws + off);                                       //   8.4 MB
    // total ~147 MB

    convert_enc_kernel<<<32768, 256, 0, stream>>>(enc, enc_bf);
    convert_w_kernel<<<512, 256, 0, stream>>>(attn_w, w_bf);
    qproj_kernel<<<8192, 256, 0, stream>>>(hidden, attn_w, attn_b, qbuf);
    scores_kernel<<<4096, 256, 0, stream>>>(enc_bf, w_bf, qbuf, vvec, spart);
    softmax_kernel<<<Bdim, 256, 0, stream>>>(spart, attnp);
    context_part_kernel<<<2048, 256, 0, stream>>>(enc_bf, attnp, cpart);
    context_reduce_kernel<<<128, 256, 0, stream>>>(cpart, out);
}